// Round 1
// baseline (3874.805 us; speedup 1.0000x reference)
//
#include <hip/hip_runtime.h>
#include <hip/hip_bf16.h>
#include <math.h>

#define T_TOK 4096
#define H_DIM 1024
#define I_DIM 512
#define E_NUM 64

// ---------------- ws layout ----------------
// counts: int[64]            @ 0
// gwT:    float[H][E]        @ 4 KiB    (256 KiB)
// lists:  int[E][T]          @ 512 KiB  (1 MiB)
// listw:  float[E][T]        @ 2 MiB    (1 MiB)

__global__ void k_transpose_gw(const float* __restrict__ gw, float* __restrict__ gwT) {
    int idx = blockIdx.x * 256 + threadIdx.x;   // 65536 = E*H
    int e = idx >> 10;
    int h = idx & 1023;
    gwT[h * E_NUM + e] = gw[idx];
}

__global__ __launch_bounds__(64) void k_router(
    const float* __restrict__ x, const float* __restrict__ gwT,
    const float* __restrict__ gate_b,
    int* __restrict__ counts, int* __restrict__ lists, float* __restrict__ listw) {
    const int lane = threadIdx.x;          // lane == expert
    const int t0 = blockIdx.x * 8;         // 8 tokens per block
    __shared__ float xs[8 * H_DIM];
    const float4* xg = (const float4*)(x + (size_t)t0 * H_DIM);
    float4* xsv = (float4*)xs;
#pragma unroll
    for (int i = 0; i < 32; ++i) xsv[lane + i * 64] = xg[lane + i * 64];
    __syncthreads();

    // fp64 accumulation: selection must not flip vs np's fp32 reference.
    double acc[8] = {0, 0, 0, 0, 0, 0, 0, 0};
    for (int h = 0; h < H_DIM; ++h) {
        double gwv = (double)gwT[h * E_NUM + lane];
#pragma unroll
        for (int j = 0; j < 8; ++j)
            acc[j] = fma((double)xs[j * H_DIM + h], gwv, acc[j]);
    }
    float bias = gate_b[lane];

    for (int j = 0; j < 8; ++j) {
        float lg = (float)acc[j] + bias;
        // top-1 (ties -> lower index, matches top_k)
        float v = lg; int idx = lane;
#pragma unroll
        for (int s = 32; s; s >>= 1) {
            float ov = __shfl_xor(v, s);
            int   oi = __shfl_xor(idx, s);
            if (ov > v || (ov == v && oi < idx)) { v = ov; idx = oi; }
        }
        float m1 = v; int i1 = idx;
        // top-2
        float v2 = (lane == i1) ? -1e30f : lg; int idx2 = lane;
#pragma unroll
        for (int s = 32; s; s >>= 1) {
            float ov = __shfl_xor(v2, s);
            int   oi = __shfl_xor(idx2, s);
            if (ov > v2 || (ov == v2 && oi < idx2)) { v2 = ov; idx2 = oi; }
        }
        if (lane == 0) {
            // renormalized top-2 softmax weights: w1 = 1/(1+e^{l2-l1})
            float p2 = expf(v2 - m1);
            float wa = 1.f / (1.f + p2);
            float wb = p2 * wa;
            int t = t0 + j;
            int p = atomicAdd(&counts[i1], 1);
            lists[i1 * T_TOK + p] = t; listw[i1 * T_TOK + p] = wa;
            p = atomicAdd(&counts[idx2], 1);
            lists[idx2 * T_TOK + p] = t; listw[idx2 * T_TOK + p] = wb;
        }
    }
}

// Grouped expert kernel: 16-token tiles per expert, fused SwiGLU + down-proj.
// LDS W tiles are [64][68] (pad) with float4 XOR swizzle -> conflict-free b128.
__global__ __launch_bounds__(256) void k_expert(
    const float* __restrict__ x,
    const float* __restrict__ W1, const float* __restrict__ W2, const float* __restrict__ W3,
    const int* __restrict__ counts, const int* __restrict__ lists,
    const float* __restrict__ listw, float* __restrict__ out) {
    const int e  = blockIdx.y;
    const int tid = threadIdx.x;
    const int tx = tid & 63;   // output column within tile (per lane)
    const int ty = tid >> 6;   // wave id: owns tokens 4*ty..4*ty+3 (wave-uniform)
    __shared__ float w1t[64][68];
    __shared__ float w3t[64][68];
    __shared__ float xt[16][68];
    __shared__ float At[16][516];
    __shared__ int   tks[16];
    __shared__ float wts[16];

    const int n = counts[e];
    const int ntiles = (n + 15) >> 4;
    const float* W1e = W1 + (size_t)e * I_DIM * H_DIM;
    const float* W3e = W3 + (size_t)e * I_DIM * H_DIM;
    const float* W2e = W2 + (size_t)e * H_DIM * I_DIM;

    for (int tile = blockIdx.x; tile < ntiles; tile += gridDim.x) {
        if (tid < 16) {
            int j = (tile << 4) + tid;
            int tk = (j < n) ? lists[e * T_TOK + j] : -1;
            tks[tid] = tk;
            wts[tid] = (j < n) ? listw[e * T_TOK + j] : 0.f;
        }
        __syncthreads();

        // ---- Phase 1: A[16][512] = silu(X W1^T) * (X W3^T) * w ----
        for (int i0 = 0; i0 < I_DIM; i0 += 64) {
            float h1a[4] = {0, 0, 0, 0};
            float h3a[4] = {0, 0, 0, 0};
            for (int k0 = 0; k0 < H_DIM; k0 += 64) {
#pragma unroll
                for (int r = 0; r < 4; ++r) {         // 64x64 tile, 4 float4/thread
                    int e4 = r * 256 + tid;
                    int ii = e4 >> 4;
                    int kq = e4 & 15;
                    int sq = kq ^ (ii & 7);           // XOR swizzle
                    float4 v1 = *(const float4*)&W1e[(size_t)(i0 + ii) * H_DIM + k0 + (kq << 2)];
                    float4 v3 = *(const float4*)&W3e[(size_t)(i0 + ii) * H_DIM + k0 + (kq << 2)];
                    *(float4*)&w1t[ii][sq << 2] = v1;
                    *(float4*)&w3t[ii][sq << 2] = v3;
                }
                {
                    int ii = tid >> 4;
                    int kq = tid & 15;
                    int tk = tks[ii];
                    float4 xv = make_float4(0.f, 0.f, 0.f, 0.f);
                    if (tk >= 0) xv = *(const float4*)&x[(size_t)tk * H_DIM + k0 + (kq << 2)];
                    *(float4*)&xt[ii][kq << 2] = xv;
                }
                __syncthreads();
#pragma unroll
                for (int k4 = 0; k4 < 16; ++k4) {
                    int sq = k4 ^ (tx & 7);
                    float4 wv1 = *(const float4*)&w1t[tx][sq << 2];
                    float4 wv3 = *(const float4*)&w3t[tx][sq << 2];
#pragma unroll
                    for (int j = 0; j < 4; ++j) {
                        float4 xv = *(const float4*)&xt[(ty << 2) + j][k4 << 2];  // wave-uniform bcast
                        h1a[j] += xv.x * wv1.x + xv.y * wv1.y + xv.z * wv1.z + xv.w * wv1.w;
                        h3a[j] += xv.x * wv3.x + xv.y * wv3.y + xv.z * wv3.z + xv.w * wv3.w;
                    }
                }
                __syncthreads();
            }
#pragma unroll
            for (int j = 0; j < 4; ++j) {
                int t = (ty << 2) + j;
                float z = h1a[j];
                float a = (z / (1.f + expf(-z))) * h3a[j] * wts[t];
                At[t][i0 + tx] = a;
            }
        }
        __syncthreads();

        // ---- Phase 2: out[t][h] += sum_i A[t][i] * W2[e][h][i] ----
        for (int h0 = 0; h0 < H_DIM; h0 += 64) {
            float oa[4] = {0, 0, 0, 0};
            for (int k0 = 0; k0 < I_DIM; k0 += 64) {
#pragma unroll
                for (int r = 0; r < 4; ++r) {
                    int e4 = r * 256 + tid;
                    int hh = e4 >> 4;
                    int kq = e4 & 15;
                    int sq = kq ^ (hh & 7);
                    *(float4*)&w1t[hh][sq << 2] =
                        *(const float4*)&W2e[(size_t)(h0 + hh) * I_DIM + k0 + (kq << 2)];
                }
                __syncthreads();
#pragma unroll
                for (int k4 = 0; k4 < 16; ++k4) {
                    int sq = k4 ^ (tx & 7);
                    float4 wv = *(const float4*)&w1t[tx][sq << 2];
#pragma unroll
                    for (int j = 0; j < 4; ++j) {
                        float4 av = *(const float4*)&At[(ty << 2) + j][k0 + (k4 << 2)];
                        oa[j] += av.x * wv.x + av.y * wv.y + av.z * wv.z + av.w * wv.w;
                    }
                }
                __syncthreads();
            }
#pragma unroll
            for (int j = 0; j < 4; ++j) {
                int tk = tks[(ty << 2) + j];
                if (tk >= 0) atomicAdd(&out[(size_t)tk * H_DIM + h0 + tx], oa[j]);
            }
        }
        __syncthreads();   // before next tile overwrites tks/At
    }
}

extern "C" void kernel_launch(void* const* d_in, const int* in_sizes, int n_in,
                              void* d_out, int out_size, void* d_ws, size_t ws_size,
                              hipStream_t stream) {
    const float* x  = (const float*)d_in[0];
    const float* gw = (const float*)d_in[1];
    const float* gb = (const float*)d_in[2];
    const float* W1 = (const float*)d_in[3];
    const float* W2 = (const float*)d_in[4];
    const float* W3 = (const float*)d_in[5];
    float* out = (float*)d_out;

    char* ws = (char*)d_ws;
    int*   counts = (int*)(ws + 0);
    float* gwT    = (float*)(ws + 4096);
    int*   lists  = (int*)(ws + (512 << 10));
    float* listw  = (float*)(ws + (2 << 20));

    hipMemsetAsync(counts, 0, E_NUM * sizeof(int), stream);
    hipMemsetAsync(out, 0, (size_t)T_TOK * H_DIM * sizeof(float), stream);

    k_transpose_gw<<<E_NUM * H_DIM / 256, 256, 0, stream>>>(gw, gwT);
    k_router<<<T_TOK / 8, 64, 0, stream>>>(x, gwT, gb, counts, lists, listw);
    k_expert<<<dim3(8, E_NUM), 256, 0, stream>>>(x, W1, W2, W3, counts, lists, listw, out);
}